// Round 4
// baseline (1104.727 us; speedup 1.0000x reference)
//
#include <hip/hip_runtime.h>
#include <math.h>

// ---------------------------------------------------------------------------
// Coherent DONN: 3 x (phase mask -> ifft2(fft2(f)*H)) -> |f|^2 -> FC(10)
// Layout: field buffer F[img][y][x] complex64 (float2), in-place passes.
// FFT: 512-pt Stockham radix-8, 64 threads (1 wave) per FFT, 3 stages.
// R4: M=32 image chunks -> 64 MB field slice stays resident in 256 MB L3
//     across all 7 passes (HBM traffic ~= compulsory x reads only).
//     Twiddles computed once per thread (forward), inverse uses conjugate.
// ---------------------------------------------------------------------------

#define PAD(i) ((i) + ((i) >> 4))      // LDS padding: breaks 16-element strides
#define LSTR 545                        // per-FFT LDS stride (float2 elements)

__device__ __forceinline__ float2 cadd(float2 a, float2 b){ return make_float2(a.x+b.x, a.y+b.y); }
__device__ __forceinline__ float2 csub(float2 a, float2 b){ return make_float2(a.x-b.x, a.y-b.y); }
__device__ __forceinline__ float2 cmul(float2 a, float2 b){ return make_float2(a.x*b.x - a.y*b.y, a.x*b.y + a.y*b.x); }

// S=-1: a*b ; S=+1: a*conj(b)  (tw tables hold FORWARD twiddles e^{-i...})
template<int S>
__device__ __forceinline__ float2 cmul_s(float2 a, float2 b) {
  return (S < 0) ? make_float2(a.x*b.x - a.y*b.y, a.x*b.y + a.y*b.x)
                 : make_float2(a.x*b.x + a.y*b.y, a.y*b.x - a.x*b.y);
}

template<int S>  // multiply by S*i  (S=-1 forward, S=+1 inverse)
__device__ __forceinline__ float2 crot(float2 z){
  return (S > 0) ? make_float2(-z.y, z.x) : make_float2(z.y, -z.x);
}

// natural-order DFT-8: V[k] = sum_n v[n] e^{S*2pi*i*nk/8}
template<int S>
__device__ __forceinline__ void fft8(float2 v[8]) {
  const float sq = 0.70710678118654752440f;
  float2 t0 = cadd(v[0], v[4]), t1 = csub(v[0], v[4]);
  float2 t2 = cadd(v[2], v[6]), t3 = csub(v[2], v[6]);
  float2 E0 = cadd(t0, t2), E2 = csub(t0, t2);
  float2 rt3 = crot<S>(t3);
  float2 E1 = cadd(t1, rt3), E3 = csub(t1, rt3);
  float2 u0 = cadd(v[1], v[5]), u1 = csub(v[1], v[5]);
  float2 u2 = cadd(v[3], v[7]), u3 = csub(v[3], v[7]);
  float2 O0 = cadd(u0, u2), O2 = csub(u0, u2);
  float2 ru3 = crot<S>(u3);
  float2 O1 = cadd(u1, ru3), O3 = csub(u1, ru3);
  float2 O1w = make_float2(sq*(O1.x - (float)S*O1.y), sq*((float)S*O1.x + O1.y));
  float2 O2w = crot<S>(O2);
  float2 O3w = make_float2(-sq*(O3.x + (float)S*O3.y), sq*((float)S*O3.x - O3.y));
  v[0] = cadd(E0, O0);  v[4] = csub(E0, O0);
  v[1] = cadd(E1, O1w); v[5] = csub(E1, O1w);
  v[2] = cadd(E2, O2w); v[6] = csub(E2, O2w);
  v[3] = cadd(E3, O3w); v[7] = csub(E3, O3w);
}

// Forward twiddle tables, computed once per thread:
// tw2[r-1] = e^{-2pi*i*r*(t&7)/64},  tw3[r-1] = e^{-2pi*i*r*(t&63)/512}, r=1..7
__device__ __forceinline__ void mktw(float2 tw2[7], float2 tw3[7], int t) {
  float a2 = -6.28318530717958647692f * (float)(t & 7) / 64.0f;
  float a3 = -6.28318530717958647692f * (float)(t & 63) / 512.0f;
  float s2, c2; __sincosf(a2, &s2, &c2);
  float s3, c3; __sincosf(a3, &s3, &c3);
  float2 w2 = make_float2(c2, s2), w3 = make_float2(c3, s3);
  tw2[0] = w2; tw3[0] = w3;
  #pragma unroll
  for (int r = 1; r < 7; ++r) { tw2[r] = cmul(tw2[r-1], w2); tw3[r] = cmul(tw3[r-1], w3); }
}

// 512-pt FFT, 64 threads (t = 0..63). On entry: v[r] = elem[t + 64r].
// On exit: v[r] = ELEM[t + 64r] (natural order). Unscaled.
template<int S>
__device__ __forceinline__ void fft512(float2 v[8], float2* __restrict__ B, int t,
                                       const float2 tw2[7], const float2 tw3[7]) {
  fft8<S>(v);                       // stage 1 (Ns=1)
  __syncthreads();
  #pragma unroll
  for (int r = 0; r < 8; ++r) B[PAD(8*t + r)] = v[r];
  __syncthreads();
  #pragma unroll
  for (int r = 0; r < 8; ++r) v[r] = B[PAD(t + 64*r)];
  __syncthreads();
  #pragma unroll
  for (int r = 1; r < 8; ++r) v[r] = cmul_s<S>(v[r], tw2[r-1]);
  fft8<S>(v);                       // stage 2 (Ns=8)
  int d = ((t >> 3) << 6) | (t & 7);
  #pragma unroll
  for (int r = 0; r < 8; ++r) B[PAD(d + 8*r)] = v[r];
  __syncthreads();
  #pragma unroll
  for (int r = 0; r < 8; ++r) v[r] = B[PAD(t + 64*r)];
  #pragma unroll
  for (int r = 1; r < 8; ++r) v[r] = cmul_s<S>(v[r], tw3[r-1]);
  fft8<S>(v);                       // stage 3 (Ns=64) -> natural order in regs
}

// ---------------------------------------------------------------------------

// Hhat = H / 512^2, fp64 phase (kz ~ 4.1e5 rad needs double reduction).
__global__ __launch_bounds__(256) void k_hinit(float2* __restrict__ Hh) {
  int idx = blockIdx.x * 256 + threadIdx.x;          // 0..262143
  int u = idx >> 9, w = idx & 511;
  double fu = (double)(u < 256 ? u : u - 512) * 1953.125;  // 1/(512*1e-6)
  double fv = (double)(w < 256 ? w : w - 512) * 1953.125;
  const double LAM = 5.32e-7, ZD = 0.035;
  const double PI = 3.14159265358979323846;
  double ang = (2.0 * PI / LAM) * ZD - PI * LAM * ZD * (fu*fu + fv*fv);
  double s, c;
  sincos(ang, &s, &c);
  const double sc = 1.0 / 262144.0;
  Hh[idx] = make_float2((float)(c * sc), (float)(s * sc));
}

// R1: field = x * e^{i*phi0}; row forward FFT.  4 rows / 256-thread block.
__global__ __launch_bounds__(256) void k_r1(const float* __restrict__ x,
                                            const float* __restrict__ ph,
                                            float2* __restrict__ F) {
  __shared__ float2 lds[4 * LSTR];
  int tid = threadIdx.x;
  int t = tid & 63, rl = tid >> 6;
  size_t row = (size_t)blockIdx.x * 4 + rl;
  int y = (int)(row & 511);
  const float* xr = x + row * 512;
  const float* pr = ph + (size_t)y * 512;
  float2 tw2[7], tw3[7];
  mktw(tw2, tw3, t);
  float2 v[8];
  #pragma unroll
  for (int r = 0; r < 8; ++r) {
    int e = t + 64*r;
    float a = xr[e];
    float p = pr[e];
    float sn, cs; __sincosf(p, &sn, &cs);
    v[r] = make_float2(a * cs, a * sn);
  }
  fft512<-1>(v, lds + rl * LSTR, t, tw2, tw3);
  float2* Fr = F + row * 512;
  #pragma unroll
  for (int r = 0; r < 8; ++r) Fr[t + 64*r] = v[r];
}

// R2/R3: row iFFT -> * e^{i*phi_l} -> row FFT (chained in registers).
__global__ __launch_bounds__(256) void k_rmid(float2* __restrict__ F,
                                              const float* __restrict__ ph) {
  __shared__ float2 lds[4 * LSTR];
  int tid = threadIdx.x;
  int t = tid & 63, rl = tid >> 6;
  size_t row = (size_t)blockIdx.x * 4 + rl;
  int y = (int)(row & 511);
  float2* Fr = F + row * 512;
  const float* pr = ph + (size_t)y * 512;
  float2 tw2[7], tw3[7];
  mktw(tw2, tw3, t);
  float2 v[8];
  #pragma unroll
  for (int r = 0; r < 8; ++r) v[r] = Fr[t + 64*r];
  fft512<1>(v, lds + rl * LSTR, t, tw2, tw3);   // unscaled inverse (1/N^2 in Hhat)
  #pragma unroll
  for (int r = 0; r < 8; ++r) {
    float p = pr[t + 64*r];
    float sn, cs; __sincosf(p, &sn, &cs);
    v[r] = cmul(v[r], make_float2(cs, sn));
  }
  fft512<-1>(v, lds + rl * LSTR, t, tw2, tw3);
  #pragma unroll
  for (int r = 0; r < 8; ++r) Fr[t + 64*r] = v[r];
}

// C: per 8-column tile: col FFT -> * Hhat -> col iFFT.  512 threads = 8 waves.
// Tile load/store vectorized to float4: 2048 float4 transfers = 4 iterations.
__global__ __launch_bounds__(512) void k_col(float2* __restrict__ F,
                                             const float2* __restrict__ H) {
  __shared__ float2 lds[8 * LSTR];
  int b = blockIdx.x >> 6;
  int x0 = (blockIdx.x & 63) << 3;
  float2* Fb = F + (size_t)b * 262144;
  float4* Fb4 = (float4*)Fb;
  int tid = threadIdx.x;
  #pragma unroll
  for (int i = 0; i < 4; ++i) {          // 16B/lane tile load (4*512 = 2048 float4)
    int f = tid + 512 * i;               // 0..2047
    int yy = f >> 2, c2 = f & 3;         // row 0..511, col-pair 0..3
    float4 d = Fb4[(size_t)yy * 256 + (x0 >> 1) + c2];
    lds[(2*c2)     * LSTR + PAD(yy)] = make_float2(d.x, d.y);
    lds[(2*c2 + 1) * LSTR + PAD(yy)] = make_float2(d.z, d.w);
  }
  int t = tid & 63, cl = tid >> 6;       // one wave per column
  float2 tw2[7], tw3[7];
  mktw(tw2, tw3, t);
  __syncthreads();
  float2* B = lds + cl * LSTR;
  float2 v[8];
  #pragma unroll
  for (int r = 0; r < 8; ++r) v[r] = B[PAD(t + 64*r)];
  fft512<-1>(v, B, t, tw2, tw3);
  // Hhat is symmetric: H[ky][x] = H[x][ky] -> lane-coalesced reads
  const float2* Hc = H + (size_t)(x0 + cl) * 512;
  #pragma unroll
  for (int r = 0; r < 8; ++r) v[r] = cmul(v[r], Hc[t + 64*r]);
  fft512<1>(v, B, t, tw2, tw3);
  __syncthreads();
  #pragma unroll
  for (int r = 0; r < 8; ++r) B[PAD(t + 64*r)] = v[r];
  __syncthreads();
  #pragma unroll
  for (int i = 0; i < 4; ++i) {          // 16B/lane tile store
    int f = tid + 512 * i;
    int yy = f >> 2, c2 = f & 3;
    float2 lo = lds[(2*c2)     * LSTR + PAD(yy)];
    float2 hi = lds[(2*c2 + 1) * LSTR + PAD(yy)];
    Fb4[(size_t)yy * 256 + (x0 >> 1) + c2] = make_float4(lo.x, lo.y, hi.x, hi.y);
  }
}

// R4: row iFFT -> intensity -> dot with 10 class rows -> partial[g][c][y].
// 4 waves of a block = SAME row y of 4 consecutive images (W rows L1-hot).
// No atomics: one store of 10 floats per wave (lanes 0..9).
__global__ __launch_bounds__(256) void k_rlast(const float2* __restrict__ F,
                                               const float* __restrict__ W,
                                               float* __restrict__ partial, int m) {
  __shared__ float2 lds[4 * LSTR];
  int tid = threadIdx.x;
  int t = tid & 63, rl = tid >> 6;
  int nq = (m + 3) >> 2;
  int y = blockIdx.x / nq;               // 0..511  (same-y blocks adjacent -> W hot in L2)
  int q = blockIdx.x - y * nq;
  int g = q * 4 + rl;                    // image within chunk
  bool act = (g < m);
  const float2* Fr = F + ((size_t)g * 262144 + (size_t)y * 512);
  float2 tw2[7], tw3[7];
  mktw(tw2, tw3, t);
  float2 v[8];
  #pragma unroll
  for (int r = 0; r < 8; ++r) v[r] = act ? Fr[t + 64*r] : make_float2(0.f, 0.f);
  fft512<1>(v, lds + rl * LSTR, t, tw2, tw3);
  float acc[10];
  #pragma unroll
  for (int c = 0; c < 10; ++c) acc[c] = 0.0f;
  const float* Wy = W + (size_t)y * 512;
  #pragma unroll
  for (int r = 0; r < 8; ++r) {
    int e = t + 64*r;
    float I = v[r].x * v[r].x + v[r].y * v[r].y;
    #pragma unroll
    for (int c = 0; c < 10; ++c) acc[c] += I * Wy[(size_t)c * 262144 + e];
  }
  float mine = 0.0f;
  #pragma unroll
  for (int c = 0; c < 10; ++c) {
    float s = acc[c];
    #pragma unroll
    for (int off = 32; off > 0; off >>= 1) s += __shfl_xor(s, off, 64);
    if (t == c) mine = s;
  }
  if (act && t < 10)
    partial[((size_t)g * 10 + t) * 512 + y] = mine;
}

// FC tail: out[g][c] = fc_b[c] + sum_y partial[g][c][y].  One wave per (g,c).
__global__ __launch_bounds__(64) void k_fc(const float* __restrict__ partial,
                                           const float* __restrict__ fc_b,
                                           float* __restrict__ out, int b0, int m) {
  int bid = blockIdx.x;                  // m*10
  int g = bid / 10, c = bid - g * 10;
  int t = threadIdx.x;
  const float* p = partial + ((size_t)g * 10 + c) * 512;
  float s = 0.0f;
  #pragma unroll
  for (int r = 0; r < 8; ++r) s += p[t + 64*r];
  #pragma unroll
  for (int off = 32; off > 0; off >>= 1) s += __shfl_xor(s, off, 64);
  if (t == 0) out[(size_t)(b0 + g) * 10 + c] = s + fc_b[c];
}

// ---------------------------------------------------------------------------

extern "C" void kernel_launch(void* const* d_in, const int* in_sizes, int n_in,
                              void* d_out, int out_size, void* d_ws, size_t ws_size,
                              hipStream_t stream) {
  const float* x    = (const float*)d_in[0];   // (128,1,512,512)
  const float* ph   = (const float*)d_in[1];   // (3,512,512)
  const float* fc_w = (const float*)d_in[2];   // (10, 262144)
  const float* fc_b = (const float*)d_in[3];   // (10,)
  float* out = (float*)d_out;                  // (128,10)

  const size_t IMG = 262144;                   // 512*512
  const size_t PER_IMG = IMG * sizeof(float2) + 512 * 10 * sizeof(float);
  float2* Hh = (float2*)d_ws;
  size_t avail = (ws_size > IMG * sizeof(float2)) ? ws_size - IMG * sizeof(float2) : 0;
  int M = (int)(avail / PER_IMG);              // images per chunk
  if (M < 1) M = 1;
  if (M > 32) M = 32;                          // 64 MB slice: stays L3-resident
  float2* F   = (float2*)((char*)d_ws + IMG * sizeof(float2));
  float* part = (float*)((char*)F + (size_t)M * IMG * sizeof(float2));

  hipLaunchKernelGGL(k_hinit, dim3(1024), dim3(256), 0, stream, Hh);

  for (int b0 = 0; b0 < 128; b0 += M) {
    int m = (128 - b0 < M) ? (128 - b0) : M;
    int rblocks = m * 128;                     // m*512 rows / 4 rows per block
    int cblocks = m * 64;                      // m * (512/8) column tiles
    int nq = (m + 3) >> 2;
    hipLaunchKernelGGL(k_r1,    dim3(rblocks), dim3(256), 0, stream, x + (size_t)b0 * IMG, ph, F);
    hipLaunchKernelGGL(k_col,   dim3(cblocks), dim3(512), 0, stream, F, (const float2*)Hh);
    hipLaunchKernelGGL(k_rmid,  dim3(rblocks), dim3(256), 0, stream, F, ph + IMG);
    hipLaunchKernelGGL(k_col,   dim3(cblocks), dim3(512), 0, stream, F, (const float2*)Hh);
    hipLaunchKernelGGL(k_rmid,  dim3(rblocks), dim3(256), 0, stream, F, ph + 2 * IMG);
    hipLaunchKernelGGL(k_col,   dim3(cblocks), dim3(512), 0, stream, F, (const float2*)Hh);
    hipLaunchKernelGGL(k_rlast, dim3(512 * nq), dim3(256), 0, stream, F, fc_w, part, m);
    hipLaunchKernelGGL(k_fc,    dim3(m * 10), dim3(64), 0, stream, part, fc_b, out, b0, m);
  }
}

// Round 5
// 975.522 us; speedup vs baseline: 1.1324x; 1.1324x over previous
//
#include <hip/hip_runtime.h>
#include <math.h>

// ---------------------------------------------------------------------------
// Coherent DONN: 3 x (phase mask -> ifft2(fft2(f)*H)) -> |f|^2 -> FC(10)
// Layout: field buffer F[img][y][x] complex64 (float2), in-place passes.
// FFT: 512-pt Stockham radix-8, 64 threads (1 wave) per FFT, 3 stages.
// R5: barrier-free FFT — each wave owns a private LDS region; same-wave
//     write->read needs only s_waitcnt lgkmcnt(0) (per-wave LDS ordering),
//     not __syncthreads. Row kernels: 0 block barriers. k_col: 2 (tile I/O).
//     M back to 128 (R4's M=32 chunking cost ~100us of launch gaps).
// ---------------------------------------------------------------------------

#define PAD(i) ((i) + ((i) >> 4))      // LDS padding: breaks 16-element strides
#define LSTR 545                        // per-FFT LDS stride (float2 elements)

// Same-wave LDS fence: all prior LDS ops complete; compiler may not reorder
// memory ops across it. Replaces __syncthreads for wave-private buffers.
__device__ __forceinline__ void wave_lds_fence() {
  asm volatile("s_waitcnt lgkmcnt(0)" ::: "memory");
}

__device__ __forceinline__ float2 cadd(float2 a, float2 b){ return make_float2(a.x+b.x, a.y+b.y); }
__device__ __forceinline__ float2 csub(float2 a, float2 b){ return make_float2(a.x-b.x, a.y-b.y); }
__device__ __forceinline__ float2 cmul(float2 a, float2 b){ return make_float2(a.x*b.x - a.y*b.y, a.x*b.y + a.y*b.x); }

// S=-1: a*b ; S=+1: a*conj(b)  (tw tables hold FORWARD twiddles e^{-i...})
template<int S>
__device__ __forceinline__ float2 cmul_s(float2 a, float2 b) {
  return (S < 0) ? make_float2(a.x*b.x - a.y*b.y, a.x*b.y + a.y*b.x)
                 : make_float2(a.x*b.x + a.y*b.y, a.y*b.x - a.x*b.y);
}

template<int S>  // multiply by S*i  (S=-1 forward, S=+1 inverse)
__device__ __forceinline__ float2 crot(float2 z){
  return (S > 0) ? make_float2(-z.y, z.x) : make_float2(z.y, -z.x);
}

// natural-order DFT-8: V[k] = sum_n v[n] e^{S*2pi*i*nk/8}
template<int S>
__device__ __forceinline__ void fft8(float2 v[8]) {
  const float sq = 0.70710678118654752440f;
  float2 t0 = cadd(v[0], v[4]), t1 = csub(v[0], v[4]);
  float2 t2 = cadd(v[2], v[6]), t3 = csub(v[2], v[6]);
  float2 E0 = cadd(t0, t2), E2 = csub(t0, t2);
  float2 rt3 = crot<S>(t3);
  float2 E1 = cadd(t1, rt3), E3 = csub(t1, rt3);
  float2 u0 = cadd(v[1], v[5]), u1 = csub(v[1], v[5]);
  float2 u2 = cadd(v[3], v[7]), u3 = csub(v[3], v[7]);
  float2 O0 = cadd(u0, u2), O2 = csub(u0, u2);
  float2 ru3 = crot<S>(u3);
  float2 O1 = cadd(u1, ru3), O3 = csub(u1, ru3);
  float2 O1w = make_float2(sq*(O1.x - (float)S*O1.y), sq*((float)S*O1.x + O1.y));
  float2 O2w = crot<S>(O2);
  float2 O3w = make_float2(-sq*(O3.x + (float)S*O3.y), sq*((float)S*O3.x - O3.y));
  v[0] = cadd(E0, O0);  v[4] = csub(E0, O0);
  v[1] = cadd(E1, O1w); v[5] = csub(E1, O1w);
  v[2] = cadd(E2, O2w); v[6] = csub(E2, O2w);
  v[3] = cadd(E3, O3w); v[7] = csub(E3, O3w);
}

// Forward twiddle tables, computed once per thread:
// tw2[r-1] = e^{-2pi*i*r*(t&7)/64},  tw3[r-1] = e^{-2pi*i*r*(t&63)/512}, r=1..7
__device__ __forceinline__ void mktw(float2 tw2[7], float2 tw3[7], int t) {
  float a2 = -6.28318530717958647692f * (float)(t & 7) / 64.0f;
  float a3 = -6.28318530717958647692f * (float)(t & 63) / 512.0f;
  float s2, c2; __sincosf(a2, &s2, &c2);
  float s3, c3; __sincosf(a3, &s3, &c3);
  float2 w2 = make_float2(c2, s2), w3 = make_float2(c3, s3);
  tw2[0] = w2; tw3[0] = w3;
  #pragma unroll
  for (int r = 1; r < 7; ++r) { tw2[r] = cmul(tw2[r-1], w2); tw3[r] = cmul(tw3[r-1], w3); }
}

// 512-pt FFT, 64 threads (t = 0..63), B = wave-PRIVATE LDS region.
// On entry: v[r] = elem[t + 64r]. On exit: v[r] = ELEM[t + 64r]. Unscaled.
// No block barriers: same-wave LDS RAW via wave_lds_fence; WAR hazards are
// covered by data dependency (every stage consumes all 8 prior reads).
template<int S>
__device__ __forceinline__ void fft512(float2 v[8], float2* __restrict__ B, int t,
                                       const float2 tw2[7], const float2 tw3[7]) {
  fft8<S>(v);                       // stage 1 (Ns=1)
  #pragma unroll
  for (int r = 0; r < 8; ++r) B[PAD(8*t + r)] = v[r];
  wave_lds_fence();
  #pragma unroll
  for (int r = 0; r < 8; ++r) v[r] = B[PAD(t + 64*r)];
  #pragma unroll
  for (int r = 1; r < 8; ++r) v[r] = cmul_s<S>(v[r], tw2[r-1]);
  fft8<S>(v);                       // stage 2 (Ns=8)
  int d = ((t >> 3) << 6) | (t & 7);
  #pragma unroll
  for (int r = 0; r < 8; ++r) B[PAD(d + 8*r)] = v[r];
  wave_lds_fence();
  #pragma unroll
  for (int r = 0; r < 8; ++r) v[r] = B[PAD(t + 64*r)];
  #pragma unroll
  for (int r = 1; r < 8; ++r) v[r] = cmul_s<S>(v[r], tw3[r-1]);
  fft8<S>(v);                       // stage 3 (Ns=64) -> natural order in regs
}

// ---------------------------------------------------------------------------

// Hhat = H / 512^2, fp64 phase (kz ~ 4.1e5 rad needs double reduction).
__global__ __launch_bounds__(256) void k_hinit(float2* __restrict__ Hh) {
  int idx = blockIdx.x * 256 + threadIdx.x;          // 0..262143
  int u = idx >> 9, w = idx & 511;
  double fu = (double)(u < 256 ? u : u - 512) * 1953.125;  // 1/(512*1e-6)
  double fv = (double)(w < 256 ? w : w - 512) * 1953.125;
  const double LAM = 5.32e-7, ZD = 0.035;
  const double PI = 3.14159265358979323846;
  double ang = (2.0 * PI / LAM) * ZD - PI * LAM * ZD * (fu*fu + fv*fv);
  double s, c;
  sincos(ang, &s, &c);
  const double sc = 1.0 / 262144.0;
  Hh[idx] = make_float2((float)(c * sc), (float)(s * sc));
}

// R1: field = x * e^{i*phi0}; row forward FFT.  4 rows / 256-thread block.
__global__ __launch_bounds__(256) void k_r1(const float* __restrict__ x,
                                            const float* __restrict__ ph,
                                            float2* __restrict__ F) {
  __shared__ float2 lds[4 * LSTR];
  int tid = threadIdx.x;
  int t = tid & 63, rl = tid >> 6;
  size_t row = (size_t)blockIdx.x * 4 + rl;
  int y = (int)(row & 511);
  const float* xr = x + row * 512;
  const float* pr = ph + (size_t)y * 512;
  float2 tw2[7], tw3[7];
  mktw(tw2, tw3, t);
  float2 v[8];
  #pragma unroll
  for (int r = 0; r < 8; ++r) {
    int e = t + 64*r;
    float a = xr[e];
    float p = pr[e];
    float sn, cs; __sincosf(p, &sn, &cs);
    v[r] = make_float2(a * cs, a * sn);
  }
  fft512<-1>(v, lds + rl * LSTR, t, tw2, tw3);
  float2* Fr = F + row * 512;
  #pragma unroll
  for (int r = 0; r < 8; ++r) Fr[t + 64*r] = v[r];
}

// R2/R3: row iFFT -> * e^{i*phi_l} -> row FFT (chained in registers).
__global__ __launch_bounds__(256) void k_rmid(float2* __restrict__ F,
                                              const float* __restrict__ ph) {
  __shared__ float2 lds[4 * LSTR];
  int tid = threadIdx.x;
  int t = tid & 63, rl = tid >> 6;
  size_t row = (size_t)blockIdx.x * 4 + rl;
  int y = (int)(row & 511);
  float2* Fr = F + row * 512;
  const float* pr = ph + (size_t)y * 512;
  float2 tw2[7], tw3[7];
  mktw(tw2, tw3, t);
  float2 v[8];
  #pragma unroll
  for (int r = 0; r < 8; ++r) v[r] = Fr[t + 64*r];
  fft512<1>(v, lds + rl * LSTR, t, tw2, tw3);   // unscaled inverse (1/N^2 in Hhat)
  #pragma unroll
  for (int r = 0; r < 8; ++r) {
    float p = pr[t + 64*r];
    float sn, cs; __sincosf(p, &sn, &cs);
    v[r] = cmul(v[r], make_float2(cs, sn));
  }
  fft512<-1>(v, lds + rl * LSTR, t, tw2, tw3);
  #pragma unroll
  for (int r = 0; r < 8; ++r) Fr[t + 64*r] = v[r];
}

// C: per 8-column tile: col FFT -> * Hhat -> col iFFT.  512 threads = 8 waves.
// Only 2 block barriers (cooperative tile load/store); FFTs are barrier-free.
__global__ __launch_bounds__(512) void k_col(float2* __restrict__ F,
                                             const float2* __restrict__ H) {
  __shared__ float2 lds[8 * LSTR];
  int b = blockIdx.x >> 6;
  int x0 = (blockIdx.x & 63) << 3;
  float2* Fb = F + (size_t)b * 262144;
  float4* Fb4 = (float4*)Fb;
  int tid = threadIdx.x;
  #pragma unroll
  for (int i = 0; i < 4; ++i) {          // 16B/lane tile load (4*512 = 2048 float4)
    int f = tid + 512 * i;               // 0..2047
    int yy = f >> 2, c2 = f & 3;         // row 0..511, col-pair 0..3
    float4 d = Fb4[(size_t)yy * 256 + (x0 >> 1) + c2];
    lds[(2*c2)     * LSTR + PAD(yy)] = make_float2(d.x, d.y);
    lds[(2*c2 + 1) * LSTR + PAD(yy)] = make_float2(d.z, d.w);
  }
  int t = tid & 63, cl = tid >> 6;       // one wave per column
  float2 tw2[7], tw3[7];
  mktw(tw2, tw3, t);
  __syncthreads();                        // tile written by other waves
  float2* B = lds + cl * LSTR;
  float2 v[8];
  #pragma unroll
  for (int r = 0; r < 8; ++r) v[r] = B[PAD(t + 64*r)];
  fft512<-1>(v, B, t, tw2, tw3);
  // Hhat is symmetric: H[ky][x] = H[x][ky] -> lane-coalesced reads
  const float2* Hc = H + (size_t)(x0 + cl) * 512;
  #pragma unroll
  for (int r = 0; r < 8; ++r) v[r] = cmul(v[r], Hc[t + 64*r]);
  fft512<1>(v, B, t, tw2, tw3);
  #pragma unroll
  for (int r = 0; r < 8; ++r) B[PAD(t + 64*r)] = v[r];
  __syncthreads();                        // before cross-wave tile store
  #pragma unroll
  for (int i = 0; i < 4; ++i) {          // 16B/lane tile store
    int f = tid + 512 * i;
    int yy = f >> 2, c2 = f & 3;
    float2 lo = lds[(2*c2)     * LSTR + PAD(yy)];
    float2 hi = lds[(2*c2 + 1) * LSTR + PAD(yy)];
    Fb4[(size_t)yy * 256 + (x0 >> 1) + c2] = make_float4(lo.x, lo.y, hi.x, hi.y);
  }
}

// R4: row iFFT -> intensity -> dot with 10 class rows -> partial[g][c][y].
// 4 waves of a block = SAME row y of 4 consecutive images (W rows L1-hot).
__global__ __launch_bounds__(256) void k_rlast(const float2* __restrict__ F,
                                               const float* __restrict__ W,
                                               float* __restrict__ partial, int m) {
  __shared__ float2 lds[4 * LSTR];
  int tid = threadIdx.x;
  int t = tid & 63, rl = tid >> 6;
  int nq = (m + 3) >> 2;
  int y = blockIdx.x / nq;               // 0..511  (same-y blocks adjacent -> W hot in L2)
  int q = blockIdx.x - y * nq;
  int g = q * 4 + rl;                    // image within chunk
  bool act = (g < m);
  const float2* Fr = F + ((size_t)g * 262144 + (size_t)y * 512);
  float2 tw2[7], tw3[7];
  mktw(tw2, tw3, t);
  float2 v[8];
  #pragma unroll
  for (int r = 0; r < 8; ++r) v[r] = act ? Fr[t + 64*r] : make_float2(0.f, 0.f);
  fft512<1>(v, lds + rl * LSTR, t, tw2, tw3);
  float acc[10];
  #pragma unroll
  for (int c = 0; c < 10; ++c) acc[c] = 0.0f;
  const float* Wy = W + (size_t)y * 512;
  #pragma unroll
  for (int r = 0; r < 8; ++r) {
    int e = t + 64*r;
    float I = v[r].x * v[r].x + v[r].y * v[r].y;
    #pragma unroll
    for (int c = 0; c < 10; ++c) acc[c] += I * Wy[(size_t)c * 262144 + e];
  }
  float mine = 0.0f;
  #pragma unroll
  for (int c = 0; c < 10; ++c) {
    float s = acc[c];
    #pragma unroll
    for (int off = 32; off > 0; off >>= 1) s += __shfl_xor(s, off, 64);
    if (t == c) mine = s;
  }
  if (act && t < 10)
    partial[((size_t)g * 10 + t) * 512 + y] = mine;
}

// FC tail: out[g][c] = fc_b[c] + sum_y partial[g][c][y].  One wave per (g,c).
__global__ __launch_bounds__(64) void k_fc(const float* __restrict__ partial,
                                           const float* __restrict__ fc_b,
                                           float* __restrict__ out, int b0, int m) {
  int bid = blockIdx.x;                  // m*10
  int g = bid / 10, c = bid - g * 10;
  int t = threadIdx.x;
  const float* p = partial + ((size_t)g * 10 + c) * 512;
  float s = 0.0f;
  #pragma unroll
  for (int r = 0; r < 8; ++r) s += p[t + 64*r];
  #pragma unroll
  for (int off = 32; off > 0; off >>= 1) s += __shfl_xor(s, off, 64);
  if (t == 0) out[(size_t)(b0 + g) * 10 + c] = s + fc_b[c];
}

// ---------------------------------------------------------------------------

extern "C" void kernel_launch(void* const* d_in, const int* in_sizes, int n_in,
                              void* d_out, int out_size, void* d_ws, size_t ws_size,
                              hipStream_t stream) {
  const float* x    = (const float*)d_in[0];   // (128,1,512,512)
  const float* ph   = (const float*)d_in[1];   // (3,512,512)
  const float* fc_w = (const float*)d_in[2];   // (10, 262144)
  const float* fc_b = (const float*)d_in[3];   // (10,)
  float* out = (float*)d_out;                  // (128,10)

  const size_t IMG = 262144;                   // 512*512
  const size_t PER_IMG = IMG * sizeof(float2) + 512 * 10 * sizeof(float);
  float2* Hh = (float2*)d_ws;
  size_t avail = (ws_size > IMG * sizeof(float2)) ? ws_size - IMG * sizeof(float2) : 0;
  int M = (int)(avail / PER_IMG);              // images per chunk
  if (M < 1) M = 1;
  if (M > 128) M = 128;                        // single chunk: 8 dispatches total
  float2* F   = (float2*)((char*)d_ws + IMG * sizeof(float2));
  float* part = (float*)((char*)F + (size_t)M * IMG * sizeof(float2));

  hipLaunchKernelGGL(k_hinit, dim3(1024), dim3(256), 0, stream, Hh);

  for (int b0 = 0; b0 < 128; b0 += M) {
    int m = (128 - b0 < M) ? (128 - b0) : M;
    int rblocks = m * 128;                     // m*512 rows / 4 rows per block
    int cblocks = m * 64;                      // m * (512/8) column tiles
    int nq = (m + 3) >> 2;
    hipLaunchKernelGGL(k_r1,    dim3(rblocks), dim3(256), 0, stream, x + (size_t)b0 * IMG, ph, F);
    hipLaunchKernelGGL(k_col,   dim3(cblocks), dim3(512), 0, stream, F, (const float2*)Hh);
    hipLaunchKernelGGL(k_rmid,  dim3(rblocks), dim3(256), 0, stream, F, ph + IMG);
    hipLaunchKernelGGL(k_col,   dim3(cblocks), dim3(512), 0, stream, F, (const float2*)Hh);
    hipLaunchKernelGGL(k_rmid,  dim3(rblocks), dim3(256), 0, stream, F, ph + 2 * IMG);
    hipLaunchKernelGGL(k_col,   dim3(cblocks), dim3(512), 0, stream, F, (const float2*)Hh);
    hipLaunchKernelGGL(k_rlast, dim3(512 * nq), dim3(256), 0, stream, F, fc_w, part, m);
    hipLaunchKernelGGL(k_fc,    dim3(m * 10), dim3(64), 0, stream, part, fc_b, out, b0, m);
  }
}

// Round 6
// 941.588 us; speedup vs baseline: 1.1733x; 1.0360x over previous
//
#include <hip/hip_runtime.h>
#include <math.h>

// ---------------------------------------------------------------------------
// Coherent DONN: 3 x (phase mask -> ifft2(fft2(f)*H)) -> |f|^2 -> FC(10)
// R6: field stored as fp16 complex (half2: re,im -> 4 B/elem) — halves HBM
//     traffic of all 7 passes (3.2 GB -> 1.7 GB). Compute stays fp32.
//     k_col uses R3-proven FFT (recomputed twiddles, 40 VGPR, block barriers);
//     row kernels keep R5 winner (twiddle tables + wave-local LDS fence).
// FFT: 512-pt Stockham radix-8, 64 threads (1 wave) per FFT, 3 stages.
// ---------------------------------------------------------------------------

#define PAD(i) ((i) + ((i) >> 4))      // LDS padding: breaks 16-element strides
#define LSTR 545                        // per-FFT LDS stride (float2 elements)

typedef __attribute__((ext_vector_type(2))) _Float16 half2v;  // 4 B field elem
typedef __attribute__((ext_vector_type(8))) _Float16 half8;   // 16 B = 4 elems

// Same-wave LDS fence: all prior LDS ops complete; compiler may not reorder.
__device__ __forceinline__ void wave_lds_fence() {
  asm volatile("s_waitcnt lgkmcnt(0)" ::: "memory");
}

__device__ __forceinline__ float2 cadd(float2 a, float2 b){ return make_float2(a.x+b.x, a.y+b.y); }
__device__ __forceinline__ float2 csub(float2 a, float2 b){ return make_float2(a.x-b.x, a.y-b.y); }
__device__ __forceinline__ float2 cmul(float2 a, float2 b){ return make_float2(a.x*b.x - a.y*b.y, a.x*b.y + a.y*b.x); }

// S=-1: a*b ; S=+1: a*conj(b)  (tw tables hold FORWARD twiddles e^{-i...})
template<int S>
__device__ __forceinline__ float2 cmul_s(float2 a, float2 b) {
  return (S < 0) ? make_float2(a.x*b.x - a.y*b.y, a.x*b.y + a.y*b.x)
                 : make_float2(a.x*b.x + a.y*b.y, a.y*b.x - a.x*b.y);
}

template<int S>  // multiply by S*i  (S=-1 forward, S=+1 inverse)
__device__ __forceinline__ float2 crot(float2 z){
  return (S > 0) ? make_float2(-z.y, z.x) : make_float2(z.y, -z.x);
}

// natural-order DFT-8: V[k] = sum_n v[n] e^{S*2pi*i*nk/8}
template<int S>
__device__ __forceinline__ void fft8(float2 v[8]) {
  const float sq = 0.70710678118654752440f;
  float2 t0 = cadd(v[0], v[4]), t1 = csub(v[0], v[4]);
  float2 t2 = cadd(v[2], v[6]), t3 = csub(v[2], v[6]);
  float2 E0 = cadd(t0, t2), E2 = csub(t0, t2);
  float2 rt3 = crot<S>(t3);
  float2 E1 = cadd(t1, rt3), E3 = csub(t1, rt3);
  float2 u0 = cadd(v[1], v[5]), u1 = csub(v[1], v[5]);
  float2 u2 = cadd(v[3], v[7]), u3 = csub(v[3], v[7]);
  float2 O0 = cadd(u0, u2), O2 = csub(u0, u2);
  float2 ru3 = crot<S>(u3);
  float2 O1 = cadd(u1, ru3), O3 = csub(u1, ru3);
  float2 O1w = make_float2(sq*(O1.x - (float)S*O1.y), sq*((float)S*O1.x + O1.y));
  float2 O2w = crot<S>(O2);
  float2 O3w = make_float2(-sq*(O3.x + (float)S*O3.y), sq*((float)S*O3.x - O3.y));
  v[0] = cadd(E0, O0);  v[4] = csub(E0, O0);
  v[1] = cadd(E1, O1w); v[5] = csub(E1, O1w);
  v[2] = cadd(E2, O2w); v[6] = csub(E2, O2w);
  v[3] = cadd(E3, O3w); v[7] = csub(E3, O3w);
}

// Per-stage twiddle recompute: v[r] *= e^{S*2pi*i * r*(t mod Ns)/(8*Ns)}
template<int S>
__device__ __forceinline__ void twid(float2 v[8], int t, int Ns) {
  float ang = (float)S * 6.28318530717958647692f * (float)(t & (Ns - 1)) / (float)(8 * Ns);
  float sn, cs;
  __sincosf(ang, &sn, &cs);
  float2 w1 = make_float2(cs, sn);
  float2 w = w1;
  v[1] = cmul(v[1], w);
  #pragma unroll
  for (int r = 2; r < 8; ++r) { w = cmul(w, w1); v[r] = cmul(v[r], w); }
}

// Forward twiddle tables (rows): tw2[r-1]=e^{-2pi*i*r*(t&7)/64}, tw3=.../512
__device__ __forceinline__ void mktw(float2 tw2[7], float2 tw3[7], int t) {
  float a2 = -6.28318530717958647692f * (float)(t & 7) / 64.0f;
  float a3 = -6.28318530717958647692f * (float)(t & 63) / 512.0f;
  float s2, c2; __sincosf(a2, &s2, &c2);
  float s3, c3; __sincosf(a3, &s3, &c3);
  float2 w2 = make_float2(c2, s2), w3 = make_float2(c3, s3);
  tw2[0] = w2; tw3[0] = w3;
  #pragma unroll
  for (int r = 1; r < 7; ++r) { tw2[r] = cmul(tw2[r-1], w2); tw3[r] = cmul(tw3[r-1], w3); }
}

// --- Variant A (k_col): block barriers + twiddle recompute (40 VGPR, R3) ---
template<int S>
__device__ __forceinline__ void fft512_b(float2 v[8], float2* __restrict__ B, int t) {
  fft8<S>(v);
  __syncthreads();
  #pragma unroll
  for (int r = 0; r < 8; ++r) B[PAD(8*t + r)] = v[r];
  __syncthreads();
  #pragma unroll
  for (int r = 0; r < 8; ++r) v[r] = B[PAD(t + 64*r)];
  __syncthreads();
  twid<S>(v, t, 8);
  fft8<S>(v);
  int d = ((t >> 3) << 6) | (t & 7);
  #pragma unroll
  for (int r = 0; r < 8; ++r) B[PAD(d + 8*r)] = v[r];
  __syncthreads();
  #pragma unroll
  for (int r = 0; r < 8; ++r) v[r] = B[PAD(t + 64*r)];
  twid<S>(v, t, 64);
  fft8<S>(v);
}

// --- Variant B (rows): wave-fenced + tables (latency-tolerant kernels) ---
template<int S>
__device__ __forceinline__ void fft512_w(float2 v[8], float2* __restrict__ B, int t,
                                         const float2 tw2[7], const float2 tw3[7]) {
  fft8<S>(v);
  #pragma unroll
  for (int r = 0; r < 8; ++r) B[PAD(8*t + r)] = v[r];
  wave_lds_fence();
  #pragma unroll
  for (int r = 0; r < 8; ++r) v[r] = B[PAD(t + 64*r)];
  #pragma unroll
  for (int r = 1; r < 8; ++r) v[r] = cmul_s<S>(v[r], tw2[r-1]);
  fft8<S>(v);
  int d = ((t >> 3) << 6) | (t & 7);
  #pragma unroll
  for (int r = 0; r < 8; ++r) B[PAD(d + 8*r)] = v[r];
  wave_lds_fence();
  #pragma unroll
  for (int r = 0; r < 8; ++r) v[r] = B[PAD(t + 64*r)];
  #pragma unroll
  for (int r = 1; r < 8; ++r) v[r] = cmul_s<S>(v[r], tw3[r-1]);
  fft8<S>(v);
}

// fp16 field element helpers
__device__ __forceinline__ float2 h2f(half2v h) { return make_float2((float)h[0], (float)h[1]); }
__device__ __forceinline__ half2v f2h(float2 v) { half2v h; h[0] = (_Float16)v.x; h[1] = (_Float16)v.y; return h; }

// ---------------------------------------------------------------------------

// Hhat = H / 512^2, fp64 phase (kz ~ 4.1e5 rad needs double reduction).
__global__ __launch_bounds__(256) void k_hinit(float2* __restrict__ Hh) {
  int idx = blockIdx.x * 256 + threadIdx.x;          // 0..262143
  int u = idx >> 9, w = idx & 511;
  double fu = (double)(u < 256 ? u : u - 512) * 1953.125;  // 1/(512*1e-6)
  double fv = (double)(w < 256 ? w : w - 512) * 1953.125;
  const double LAM = 5.32e-7, ZD = 0.035;
  const double PI = 3.14159265358979323846;
  double ang = (2.0 * PI / LAM) * ZD - PI * LAM * ZD * (fu*fu + fv*fv);
  double s, c;
  sincos(ang, &s, &c);
  const double sc = 1.0 / 262144.0;
  Hh[idx] = make_float2((float)(c * sc), (float)(s * sc));
}

// R1: field = x * e^{i*phi0}; row forward FFT.  4 rows / 256-thread block.
__global__ __launch_bounds__(256) void k_r1(const float* __restrict__ x,
                                            const float* __restrict__ ph,
                                            half2v* __restrict__ F) {
  __shared__ float2 lds[4 * LSTR];
  int tid = threadIdx.x;
  int t = tid & 63, rl = tid >> 6;
  size_t row = (size_t)blockIdx.x * 4 + rl;
  int y = (int)(row & 511);
  const float* xr = x + row * 512;
  const float* pr = ph + (size_t)y * 512;
  float2 tw2[7], tw3[7];
  mktw(tw2, tw3, t);
  float2 v[8];
  #pragma unroll
  for (int r = 0; r < 8; ++r) {
    int e = t + 64*r;
    float a = xr[e];
    float p = pr[e];
    float sn, cs; __sincosf(p, &sn, &cs);
    v[r] = make_float2(a * cs, a * sn);
  }
  fft512_w<-1>(v, lds + rl * LSTR, t, tw2, tw3);
  half2v* Fr = F + row * 512;
  #pragma unroll
  for (int r = 0; r < 8; ++r) Fr[t + 64*r] = f2h(v[r]);
}

// R2/R3: row iFFT -> * e^{i*phi_l} -> row FFT (chained in registers).
__global__ __launch_bounds__(256) void k_rmid(half2v* __restrict__ F,
                                              const float* __restrict__ ph) {
  __shared__ float2 lds[4 * LSTR];
  int tid = threadIdx.x;
  int t = tid & 63, rl = tid >> 6;
  size_t row = (size_t)blockIdx.x * 4 + rl;
  int y = (int)(row & 511);
  half2v* Fr = F + row * 512;
  const float* pr = ph + (size_t)y * 512;
  float2 tw2[7], tw3[7];
  mktw(tw2, tw3, t);
  float2 v[8];
  #pragma unroll
  for (int r = 0; r < 8; ++r) v[r] = h2f(Fr[t + 64*r]);
  fft512_w<1>(v, lds + rl * LSTR, t, tw2, tw3);  // unscaled inverse (1/N^2 in Hhat)
  #pragma unroll
  for (int r = 0; r < 8; ++r) {
    float p = pr[t + 64*r];
    float sn, cs; __sincosf(p, &sn, &cs);
    v[r] = cmul(v[r], make_float2(cs, sn));
  }
  fft512_w<-1>(v, lds + rl * LSTR, t, tw2, tw3);
  #pragma unroll
  for (int r = 0; r < 8; ++r) Fr[t + 64*r] = f2h(v[r]);
}

// C: per 8-column tile: col FFT -> * Hhat -> col iFFT.  512 threads = 8 waves.
// fp16 tile: 16B/lane = 4 elems -> 2 half8 per row, 2 coop iterations.
__global__ __launch_bounds__(512) void k_col(half2v* __restrict__ F,
                                             const float2* __restrict__ H) {
  __shared__ float2 lds[8 * LSTR];
  int b = blockIdx.x >> 6;
  int x0 = (blockIdx.x & 63) << 3;
  half2v* Fb = F + (size_t)b * 262144;
  half8* Fb8 = (half8*)Fb;               // 4 elems per half8; row stride 128
  int tid = threadIdx.x;
  #pragma unroll
  for (int i = 0; i < 2; ++i) {          // tile load: 1024 half8 = 2 iters
    int f = tid + 512 * i;               // 0..1023
    int yy = f >> 1, c4 = f & 1;         // row 0..511, half8-within-row 0..1
    half8 d = Fb8[(size_t)yy * 128 + (x0 >> 2) + c4];
    #pragma unroll
    for (int k = 0; k < 4; ++k)
      lds[(4*c4 + k) * LSTR + PAD(yy)] =
        make_float2((float)d[2*k], (float)d[2*k + 1]);
  }
  __syncthreads();
  int t = tid & 63, cl = tid >> 6;       // one wave per column
  float2* B = lds + cl * LSTR;
  float2 v[8];
  #pragma unroll
  for (int r = 0; r < 8; ++r) v[r] = B[PAD(t + 64*r)];
  fft512_b<-1>(v, B, t);
  // Hhat is symmetric: H[ky][x] = H[x][ky] -> lane-coalesced reads
  const float2* Hc = H + (size_t)(x0 + cl) * 512;
  #pragma unroll
  for (int r = 0; r < 8; ++r) v[r] = cmul(v[r], Hc[t + 64*r]);
  fft512_b<1>(v, B, t);
  __syncthreads();
  #pragma unroll
  for (int r = 0; r < 8; ++r) B[PAD(t + 64*r)] = v[r];
  __syncthreads();
  #pragma unroll
  for (int i = 0; i < 2; ++i) {          // tile store
    int f = tid + 512 * i;
    int yy = f >> 1, c4 = f & 1;
    half8 o;
    #pragma unroll
    for (int k = 0; k < 4; ++k) {
      float2 e = lds[(4*c4 + k) * LSTR + PAD(yy)];
      o[2*k] = (_Float16)e.x; o[2*k + 1] = (_Float16)e.y;
    }
    Fb8[(size_t)yy * 128 + (x0 >> 2) + c4] = o;
  }
}

// R4: row iFFT -> intensity -> dot with 10 class rows -> partial[g][c][y].
__global__ __launch_bounds__(256) void k_rlast(const half2v* __restrict__ F,
                                               const float* __restrict__ W,
                                               float* __restrict__ partial, int m) {
  __shared__ float2 lds[4 * LSTR];
  int tid = threadIdx.x;
  int t = tid & 63, rl = tid >> 6;
  int nq = (m + 3) >> 2;
  int y = blockIdx.x / nq;               // same-y blocks adjacent -> W hot in L2
  int q = blockIdx.x - y * nq;
  int g = q * 4 + rl;                    // image within chunk
  bool act = (g < m);
  const half2v* Fr = F + ((size_t)g * 262144 + (size_t)y * 512);
  float2 tw2[7], tw3[7];
  mktw(tw2, tw3, t);
  float2 v[8];
  #pragma unroll
  for (int r = 0; r < 8; ++r) {
    half2v h = act ? Fr[t + 64*r] : (half2v)(_Float16)0.0f;
    v[r] = h2f(h);
  }
  fft512_w<1>(v, lds + rl * LSTR, t, tw2, tw3);
  float acc[10];
  #pragma unroll
  for (int c = 0; c < 10; ++c) acc[c] = 0.0f;
  const float* Wy = W + (size_t)y * 512;
  #pragma unroll
  for (int r = 0; r < 8; ++r) {
    int e = t + 64*r;
    float I = v[r].x * v[r].x + v[r].y * v[r].y;
    #pragma unroll
    for (int c = 0; c < 10; ++c) acc[c] += I * Wy[(size_t)c * 262144 + e];
  }
  float mine = 0.0f;
  #pragma unroll
  for (int c = 0; c < 10; ++c) {
    float s = acc[c];
    #pragma unroll
    for (int off = 32; off > 0; off >>= 1) s += __shfl_xor(s, off, 64);
    if (t == c) mine = s;
  }
  if (act && t < 10)
    partial[((size_t)g * 10 + t) * 512 + y] = mine;
}

// FC tail: out[g][c] = fc_b[c] + sum_y partial[g][c][y].  One wave per (g,c).
__global__ __launch_bounds__(64) void k_fc(const float* __restrict__ partial,
                                           const float* __restrict__ fc_b,
                                           float* __restrict__ out, int b0, int m) {
  int bid = blockIdx.x;                  // m*10
  int g = bid / 10, c = bid - g * 10;
  int t = threadIdx.x;
  const float* p = partial + ((size_t)g * 10 + c) * 512;
  float s = 0.0f;
  #pragma unroll
  for (int r = 0; r < 8; ++r) s += p[t + 64*r];
  #pragma unroll
  for (int off = 32; off > 0; off >>= 1) s += __shfl_xor(s, off, 64);
  if (t == 0) out[(size_t)(b0 + g) * 10 + c] = s + fc_b[c];
}

// ---------------------------------------------------------------------------

extern "C" void kernel_launch(void* const* d_in, const int* in_sizes, int n_in,
                              void* d_out, int out_size, void* d_ws, size_t ws_size,
                              hipStream_t stream) {
  const float* x    = (const float*)d_in[0];   // (128,1,512,512)
  const float* ph   = (const float*)d_in[1];   // (3,512,512)
  const float* fc_w = (const float*)d_in[2];   // (10, 262144)
  const float* fc_b = (const float*)d_in[3];   // (10,)
  float* out = (float*)d_out;                  // (128,10)

  const size_t IMG = 262144;                   // 512*512
  const size_t PER_IMG = IMG * sizeof(half2v) + 512 * 10 * sizeof(float);
  float2* Hh = (float2*)d_ws;
  size_t avail = (ws_size > IMG * sizeof(float2)) ? ws_size - IMG * sizeof(float2) : 0;
  int M = (int)(avail / PER_IMG);              // images per chunk
  if (M < 1) M = 1;
  if (M > 128) M = 128;                        // single chunk: 9 dispatches total
  half2v* F  = (half2v*)((char*)d_ws + IMG * sizeof(float2));
  float* part = (float*)((char*)F + (size_t)M * IMG * sizeof(half2v));

  hipLaunchKernelGGL(k_hinit, dim3(1024), dim3(256), 0, stream, Hh);

  for (int b0 = 0; b0 < 128; b0 += M) {
    int m = (128 - b0 < M) ? (128 - b0) : M;
    int rblocks = m * 128;                     // m*512 rows / 4 rows per block
    int cblocks = m * 64;                      // m * (512/8) column tiles
    int nq = (m + 3) >> 2;
    hipLaunchKernelGGL(k_r1,    dim3(rblocks), dim3(256), 0, stream, x + (size_t)b0 * IMG, ph, F);
    hipLaunchKernelGGL(k_col,   dim3(cblocks), dim3(512), 0, stream, F, (const float2*)Hh);
    hipLaunchKernelGGL(k_rmid,  dim3(rblocks), dim3(256), 0, stream, F, ph + IMG);
    hipLaunchKernelGGL(k_col,   dim3(cblocks), dim3(512), 0, stream, F, (const float2*)Hh);
    hipLaunchKernelGGL(k_rmid,  dim3(rblocks), dim3(256), 0, stream, F, ph + 2 * IMG);
    hipLaunchKernelGGL(k_col,   dim3(cblocks), dim3(512), 0, stream, F, (const float2*)Hh);
    hipLaunchKernelGGL(k_rlast, dim3(512 * nq), dim3(256), 0, stream, F, fc_w, part, m);
    hipLaunchKernelGGL(k_fc,    dim3(m * 10), dim3(64), 0, stream, part, fc_b, out, b0, m);
  }
}

// Round 7
// 872.064 us; speedup vs baseline: 1.2668x; 1.0797x over previous
//
#include <hip/hip_runtime.h>
#include <math.h>

// ---------------------------------------------------------------------------
// Coherent DONN: 3 x (phase mask -> ifft2(fft2(f)*H)) -> |f|^2 -> FC(10)
// R7: k_col rebuilt — 16-column tiles (64 B/row-segment = full cache line,
//     kills the 2x fp16 read amplification seen in R6: FETCH 272 MB for a
//     128 MB field) + wave-fenced FFT with recomputed twiddles (2 block
//     barriers/block instead of 13, VGPR ~40 so no R5 occupancy cliff).
//     1024 threads = 16 waves, one wave per column. Rows keep R5/R6 form.
// Field stored fp16 complex (half2v, 4 B/elem); compute fp32.
// FFT: 512-pt Stockham radix-8, 64 threads (1 wave) per FFT, 3 stages.
// ---------------------------------------------------------------------------

#define PAD(i) ((i) + ((i) >> 4))      // LDS padding: breaks 16-element strides
#define LSTR 545                        // per-FFT LDS stride (float2 elements)

typedef __attribute__((ext_vector_type(2))) _Float16 half2v;  // 4 B field elem
typedef __attribute__((ext_vector_type(8))) _Float16 half8;   // 16 B = 4 elems

// Same-wave LDS fence: all prior LDS ops complete; compiler may not reorder.
__device__ __forceinline__ void wave_lds_fence() {
  asm volatile("s_waitcnt lgkmcnt(0)" ::: "memory");
}

__device__ __forceinline__ float2 cadd(float2 a, float2 b){ return make_float2(a.x+b.x, a.y+b.y); }
__device__ __forceinline__ float2 csub(float2 a, float2 b){ return make_float2(a.x-b.x, a.y-b.y); }
__device__ __forceinline__ float2 cmul(float2 a, float2 b){ return make_float2(a.x*b.x - a.y*b.y, a.x*b.y + a.y*b.x); }

// S=-1: a*b ; S=+1: a*conj(b)  (tw tables hold FORWARD twiddles e^{-i...})
template<int S>
__device__ __forceinline__ float2 cmul_s(float2 a, float2 b) {
  return (S < 0) ? make_float2(a.x*b.x - a.y*b.y, a.x*b.y + a.y*b.x)
                 : make_float2(a.x*b.x + a.y*b.y, a.y*b.x - a.x*b.y);
}

template<int S>  // multiply by S*i  (S=-1 forward, S=+1 inverse)
__device__ __forceinline__ float2 crot(float2 z){
  return (S > 0) ? make_float2(-z.y, z.x) : make_float2(z.y, -z.x);
}

// natural-order DFT-8: V[k] = sum_n v[n] e^{S*2pi*i*nk/8}
template<int S>
__device__ __forceinline__ void fft8(float2 v[8]) {
  const float sq = 0.70710678118654752440f;
  float2 t0 = cadd(v[0], v[4]), t1 = csub(v[0], v[4]);
  float2 t2 = cadd(v[2], v[6]), t3 = csub(v[2], v[6]);
  float2 E0 = cadd(t0, t2), E2 = csub(t0, t2);
  float2 rt3 = crot<S>(t3);
  float2 E1 = cadd(t1, rt3), E3 = csub(t1, rt3);
  float2 u0 = cadd(v[1], v[5]), u1 = csub(v[1], v[5]);
  float2 u2 = cadd(v[3], v[7]), u3 = csub(v[3], v[7]);
  float2 O0 = cadd(u0, u2), O2 = csub(u0, u2);
  float2 ru3 = crot<S>(u3);
  float2 O1 = cadd(u1, ru3), O3 = csub(u1, ru3);
  float2 O1w = make_float2(sq*(O1.x - (float)S*O1.y), sq*((float)S*O1.x + O1.y));
  float2 O2w = crot<S>(O2);
  float2 O3w = make_float2(-sq*(O3.x + (float)S*O3.y), sq*((float)S*O3.x - O3.y));
  v[0] = cadd(E0, O0);  v[4] = csub(E0, O0);
  v[1] = cadd(E1, O1w); v[5] = csub(E1, O1w);
  v[2] = cadd(E2, O2w); v[6] = csub(E2, O2w);
  v[3] = cadd(E3, O3w); v[7] = csub(E3, O3w);
}

// Per-stage twiddle recompute: v[r] *= e^{S*2pi*i * r*(t mod Ns)/(8*Ns)}
template<int S>
__device__ __forceinline__ void twid(float2 v[8], int t, int Ns) {
  float ang = (float)S * 6.28318530717958647692f * (float)(t & (Ns - 1)) / (float)(8 * Ns);
  float sn, cs;
  __sincosf(ang, &sn, &cs);
  float2 w1 = make_float2(cs, sn);
  float2 w = w1;
  v[1] = cmul(v[1], w);
  #pragma unroll
  for (int r = 2; r < 8; ++r) { w = cmul(w, w1); v[r] = cmul(v[r], w); }
}

// Forward twiddle tables (rows): tw2[r-1]=e^{-2pi*i*r*(t&7)/64}, tw3=.../512
__device__ __forceinline__ void mktw(float2 tw2[7], float2 tw3[7], int t) {
  float a2 = -6.28318530717958647692f * (float)(t & 7) / 64.0f;
  float a3 = -6.28318530717958647692f * (float)(t & 63) / 512.0f;
  float s2, c2; __sincosf(a2, &s2, &c2);
  float s3, c3; __sincosf(a3, &s3, &c3);
  float2 w2 = make_float2(c2, s2), w3 = make_float2(c3, s3);
  tw2[0] = w2; tw3[0] = w3;
  #pragma unroll
  for (int r = 1; r < 7; ++r) { tw2[r] = cmul(tw2[r-1], w2); tw3[r] = cmul(tw3[r-1], w3); }
}

// --- Variant B (rows): wave-fenced + tables (latency-tolerant kernels) ---
template<int S>
__device__ __forceinline__ void fft512_w(float2 v[8], float2* __restrict__ B, int t,
                                         const float2 tw2[7], const float2 tw3[7]) {
  fft8<S>(v);
  #pragma unroll
  for (int r = 0; r < 8; ++r) B[PAD(8*t + r)] = v[r];
  wave_lds_fence();
  #pragma unroll
  for (int r = 0; r < 8; ++r) v[r] = B[PAD(t + 64*r)];
  #pragma unroll
  for (int r = 1; r < 8; ++r) v[r] = cmul_s<S>(v[r], tw2[r-1]);
  fft8<S>(v);
  int d = ((t >> 3) << 6) | (t & 7);
  #pragma unroll
  for (int r = 0; r < 8; ++r) B[PAD(d + 8*r)] = v[r];
  wave_lds_fence();
  #pragma unroll
  for (int r = 0; r < 8; ++r) v[r] = B[PAD(t + 64*r)];
  #pragma unroll
  for (int r = 1; r < 8; ++r) v[r] = cmul_s<S>(v[r], tw3[r-1]);
  fft8<S>(v);
}

// --- Variant C (k_col): wave-fenced + twiddle recompute (low VGPR) ---
template<int S>
__device__ __forceinline__ void fft512_f(float2 v[8], float2* __restrict__ B, int t) {
  fft8<S>(v);
  #pragma unroll
  for (int r = 0; r < 8; ++r) B[PAD(8*t + r)] = v[r];
  wave_lds_fence();
  #pragma unroll
  for (int r = 0; r < 8; ++r) v[r] = B[PAD(t + 64*r)];
  twid<S>(v, t, 8);
  fft8<S>(v);
  int d = ((t >> 3) << 6) | (t & 7);
  #pragma unroll
  for (int r = 0; r < 8; ++r) B[PAD(d + 8*r)] = v[r];
  wave_lds_fence();
  #pragma unroll
  for (int r = 0; r < 8; ++r) v[r] = B[PAD(t + 64*r)];
  twid<S>(v, t, 64);
  fft8<S>(v);
}

// fp16 field element helpers
__device__ __forceinline__ float2 h2f(half2v h) { return make_float2((float)h[0], (float)h[1]); }
__device__ __forceinline__ half2v f2h(float2 v) { half2v h; h[0] = (_Float16)v.x; h[1] = (_Float16)v.y; return h; }

// ---------------------------------------------------------------------------

// Hhat = H / 512^2, fp64 phase (kz ~ 4.1e5 rad needs double reduction).
__global__ __launch_bounds__(256) void k_hinit(float2* __restrict__ Hh) {
  int idx = blockIdx.x * 256 + threadIdx.x;          // 0..262143
  int u = idx >> 9, w = idx & 511;
  double fu = (double)(u < 256 ? u : u - 512) * 1953.125;  // 1/(512*1e-6)
  double fv = (double)(w < 256 ? w : w - 512) * 1953.125;
  const double LAM = 5.32e-7, ZD = 0.035;
  const double PI = 3.14159265358979323846;
  double ang = (2.0 * PI / LAM) * ZD - PI * LAM * ZD * (fu*fu + fv*fv);
  double s, c;
  sincos(ang, &s, &c);
  const double sc = 1.0 / 262144.0;
  Hh[idx] = make_float2((float)(c * sc), (float)(s * sc));
}

// R1: field = x * e^{i*phi0}; row forward FFT.  4 rows / 256-thread block.
__global__ __launch_bounds__(256) void k_r1(const float* __restrict__ x,
                                            const float* __restrict__ ph,
                                            half2v* __restrict__ F) {
  __shared__ float2 lds[4 * LSTR];
  int tid = threadIdx.x;
  int t = tid & 63, rl = tid >> 6;
  size_t row = (size_t)blockIdx.x * 4 + rl;
  int y = (int)(row & 511);
  const float* xr = x + row * 512;
  const float* pr = ph + (size_t)y * 512;
  float2 tw2[7], tw3[7];
  mktw(tw2, tw3, t);
  float2 v[8];
  #pragma unroll
  for (int r = 0; r < 8; ++r) {
    int e = t + 64*r;
    float a = xr[e];
    float p = pr[e];
    float sn, cs; __sincosf(p, &sn, &cs);
    v[r] = make_float2(a * cs, a * sn);
  }
  fft512_w<-1>(v, lds + rl * LSTR, t, tw2, tw3);
  half2v* Fr = F + row * 512;
  #pragma unroll
  for (int r = 0; r < 8; ++r) Fr[t + 64*r] = f2h(v[r]);
}

// R2/R3: row iFFT -> * e^{i*phi_l} -> row FFT (chained in registers).
__global__ __launch_bounds__(256) void k_rmid(half2v* __restrict__ F,
                                              const float* __restrict__ ph) {
  __shared__ float2 lds[4 * LSTR];
  int tid = threadIdx.x;
  int t = tid & 63, rl = tid >> 6;
  size_t row = (size_t)blockIdx.x * 4 + rl;
  int y = (int)(row & 511);
  half2v* Fr = F + row * 512;
  const float* pr = ph + (size_t)y * 512;
  float2 tw2[7], tw3[7];
  mktw(tw2, tw3, t);
  float2 v[8];
  #pragma unroll
  for (int r = 0; r < 8; ++r) v[r] = h2f(Fr[t + 64*r]);
  fft512_w<1>(v, lds + rl * LSTR, t, tw2, tw3);  // unscaled inverse (1/N^2 in Hhat)
  #pragma unroll
  for (int r = 0; r < 8; ++r) {
    float p = pr[t + 64*r];
    float sn, cs; __sincosf(p, &sn, &cs);
    v[r] = cmul(v[r], make_float2(cs, sn));
  }
  fft512_w<-1>(v, lds + rl * LSTR, t, tw2, tw3);
  #pragma unroll
  for (int r = 0; r < 8; ++r) Fr[t + 64*r] = f2h(v[r]);
}

// C: per 16-column tile: col FFT -> * Hhat -> col iFFT.
// 1024 threads = 16 waves, one wave per column. Row-segment = 16 cols * 4 B
// = 64 B = full cache line (no fp16 read amplification). 2 block barriers.
__global__ __launch_bounds__(1024) void k_col(half2v* __restrict__ F,
                                              const float2* __restrict__ H) {
  __shared__ float2 lds[16 * LSTR];      // 69.8 KB -> 2 blocks/CU
  int b = blockIdx.x >> 5;               // image
  int x0 = (blockIdx.x & 31) << 4;       // tile base column (16-col tiles)
  half2v* Fb = F + (size_t)b * 262144;
  half8* Fb8 = (half8*)Fb;               // 4 elems per half8; row stride 128
  int tid = threadIdx.x;
  #pragma unroll
  for (int i = 0; i < 2; ++i) {          // tile load: 2048 half8 = 2 iters
    int f = tid + 1024 * i;              // 0..2047
    int yy = f >> 2, c4 = f & 3;         // row 0..511, half8-within-row 0..3
    half8 d = Fb8[(size_t)yy * 128 + (x0 >> 2) + c4];
    #pragma unroll
    for (int k = 0; k < 4; ++k)
      lds[(4*c4 + k) * LSTR + PAD(yy)] =
        make_float2((float)d[2*k], (float)d[2*k + 1]);
  }
  __syncthreads();
  int t = tid & 63, cl = tid >> 6;       // one wave per column (cl 0..15)
  float2* B = lds + cl * LSTR;
  float2 v[8];
  #pragma unroll
  for (int r = 0; r < 8; ++r) v[r] = B[PAD(t + 64*r)];
  fft512_f<-1>(v, B, t);
  // Hhat is symmetric: H[ky][x] = H[x][ky] -> lane-coalesced reads
  const float2* Hc = H + (size_t)(x0 + cl) * 512;
  #pragma unroll
  for (int r = 0; r < 8; ++r) v[r] = cmul(v[r], Hc[t + 64*r]);
  fft512_f<1>(v, B, t);
  #pragma unroll
  for (int r = 0; r < 8; ++r) B[PAD(t + 64*r)] = v[r];
  __syncthreads();                        // before cross-wave tile store
  #pragma unroll
  for (int i = 0; i < 2; ++i) {          // tile store (full 64-B lines)
    int f = tid + 1024 * i;
    int yy = f >> 2, c4 = f & 3;
    half8 o;
    #pragma unroll
    for (int k = 0; k < 4; ++k) {
      float2 e = lds[(4*c4 + k) * LSTR + PAD(yy)];
      o[2*k] = (_Float16)e.x; o[2*k + 1] = (_Float16)e.y;
    }
    Fb8[(size_t)yy * 128 + (x0 >> 2) + c4] = o;
  }
}

// R4: row iFFT -> intensity -> dot with 10 class rows -> partial[g][c][y].
__global__ __launch_bounds__(256) void k_rlast(const half2v* __restrict__ F,
                                               const float* __restrict__ W,
                                               float* __restrict__ partial, int m) {
  __shared__ float2 lds[4 * LSTR];
  int tid = threadIdx.x;
  int t = tid & 63, rl = tid >> 6;
  int nq = (m + 3) >> 2;
  int y = blockIdx.x / nq;               // same-y blocks adjacent -> W hot in L2
  int q = blockIdx.x - y * nq;
  int g = q * 4 + rl;                    // image within chunk
  bool act = (g < m);
  const half2v* Fr = F + ((size_t)g * 262144 + (size_t)y * 512);
  float2 tw2[7], tw3[7];
  mktw(tw2, tw3, t);
  float2 v[8];
  #pragma unroll
  for (int r = 0; r < 8; ++r) {
    half2v h = act ? Fr[t + 64*r] : (half2v)(_Float16)0.0f;
    v[r] = h2f(h);
  }
  fft512_w<1>(v, lds + rl * LSTR, t, tw2, tw3);
  float acc[10];
  #pragma unroll
  for (int c = 0; c < 10; ++c) acc[c] = 0.0f;
  const float* Wy = W + (size_t)y * 512;
  #pragma unroll
  for (int r = 0; r < 8; ++r) {
    int e = t + 64*r;
    float I = v[r].x * v[r].x + v[r].y * v[r].y;
    #pragma unroll
    for (int c = 0; c < 10; ++c) acc[c] += I * Wy[(size_t)c * 262144 + e];
  }
  float mine = 0.0f;
  #pragma unroll
  for (int c = 0; c < 10; ++c) {
    float s = acc[c];
    #pragma unroll
    for (int off = 32; off > 0; off >>= 1) s += __shfl_xor(s, off, 64);
    if (t == c) mine = s;
  }
  if (act && t < 10)
    partial[((size_t)g * 10 + t) * 512 + y] = mine;
}

// FC tail: out[g][c] = fc_b[c] + sum_y partial[g][c][y].  One wave per (g,c).
__global__ __launch_bounds__(64) void k_fc(const float* __restrict__ partial,
                                           const float* __restrict__ fc_b,
                                           float* __restrict__ out, int b0, int m) {
  int bid = blockIdx.x;                  // m*10
  int g = bid / 10, c = bid - g * 10;
  int t = threadIdx.x;
  const float* p = partial + ((size_t)g * 10 + c) * 512;
  float s = 0.0f;
  #pragma unroll
  for (int r = 0; r < 8; ++r) s += p[t + 64*r];
  #pragma unroll
  for (int off = 32; off > 0; off >>= 1) s += __shfl_xor(s, off, 64);
  if (t == 0) out[(size_t)(b0 + g) * 10 + c] = s + fc_b[c];
}

// ---------------------------------------------------------------------------

extern "C" void kernel_launch(void* const* d_in, const int* in_sizes, int n_in,
                              void* d_out, int out_size, void* d_ws, size_t ws_size,
                              hipStream_t stream) {
  const float* x    = (const float*)d_in[0];   // (128,1,512,512)
  const float* ph   = (const float*)d_in[1];   // (3,512,512)
  const float* fc_w = (const float*)d_in[2];   // (10, 262144)
  const float* fc_b = (const float*)d_in[3];   // (10,)
  float* out = (float*)d_out;                  // (128,10)

  const size_t IMG = 262144;                   // 512*512
  const size_t PER_IMG = IMG * sizeof(half2v) + 512 * 10 * sizeof(float);
  float2* Hh = (float2*)d_ws;
  size_t avail = (ws_size > IMG * sizeof(float2)) ? ws_size - IMG * sizeof(float2) : 0;
  int M = (int)(avail / PER_IMG);              // images per chunk
  if (M < 1) M = 1;
  if (M > 128) M = 128;                        // single chunk: 9 dispatches total
  half2v* F  = (half2v*)((char*)d_ws + IMG * sizeof(float2));
  float* part = (float*)((char*)F + (size_t)M * IMG * sizeof(half2v));

  hipLaunchKernelGGL(k_hinit, dim3(1024), dim3(256), 0, stream, Hh);

  for (int b0 = 0; b0 < 128; b0 += M) {
    int m = (128 - b0 < M) ? (128 - b0) : M;
    int rblocks = m * 128;                     // m*512 rows / 4 rows per block
    int cblocks = m * 32;                      // m * (512/16) column tiles
    int nq = (m + 3) >> 2;
    hipLaunchKernelGGL(k_r1,    dim3(rblocks), dim3(256), 0, stream, x + (size_t)b0 * IMG, ph, F);
    hipLaunchKernelGGL(k_col,   dim3(cblocks), dim3(1024), 0, stream, F, (const float2*)Hh);
    hipLaunchKernelGGL(k_rmid,  dim3(rblocks), dim3(256), 0, stream, F, ph + IMG);
    hipLaunchKernelGGL(k_col,   dim3(cblocks), dim3(1024), 0, stream, F, (const float2*)Hh);
    hipLaunchKernelGGL(k_rmid,  dim3(rblocks), dim3(256), 0, stream, F, ph + 2 * IMG);
    hipLaunchKernelGGL(k_col,   dim3(cblocks), dim3(1024), 0, stream, F, (const float2*)Hh);
    hipLaunchKernelGGL(k_rlast, dim3(512 * nq), dim3(256), 0, stream, F, fc_w, part, m);
    hipLaunchKernelGGL(k_fc,    dim3(m * 10), dim3(64), 0, stream, part, fc_b, out, b0, m);
  }
}